// Round 5
// baseline (285.793 us; speedup 1.0000x reference)
//
#include <hip/hip_runtime.h>

#define D 128
#define BNODES 128       // nodes per bin / fused block
#define NBIN 782         // ceil(100000/128)
#define NBMAX 1024
#define CHUNK 2048       // edges per cfill chunk
#define SCAP 6           // fused: staged edges per thread (6*512=3072 cap, mean 2048)
#define ORDCAP 3072
#define HB 128           // histogram partial blocks

typedef __attribute__((ext_vector_type(8))) short bf16x8;
typedef __attribute__((ext_vector_type(4))) float f32x4;

__device__ __forceinline__ unsigned short f2bf(float f) {
    unsigned int u = __builtin_bit_cast(unsigned int, f);
    u = (u + 0x7fffu + ((u >> 16) & 1u)) >> 16;
    return (unsigned short)u;
}
__device__ __forceinline__ float bf2f(unsigned int u) {
    return __builtin_bit_cast(float, u << 16);
}

// Fused prep: x fp32->bf16, W transpose->bf16, coarse-histogram partials.
__global__ void prep_kernel(const float* __restrict__ x,
                            unsigned short* __restrict__ x_bf,
                            const float* __restrict__ W,
                            unsigned short* __restrict__ WT,
                            const int* __restrict__ edst,
                            int* __restrict__ hpart,
                            int n4, int XB, int WB, int E) {
    __shared__ int h[NBMAX];
    int blk = blockIdx.x, tid = threadIdx.x;
    if (blk < XB) {
        int i = blk * 256 + tid;
        if (i < n4) {
            float4 v = ((const float4*)x)[i];
            ushort4 s;
            s.x = f2bf(v.x); s.y = f2bf(v.y); s.z = f2bf(v.z); s.w = f2bf(v.w);
            ((ushort4*)x_bf)[i] = s;
        }
    } else if (blk < XB + WB) {
        int t = (blk - XB) * 256 + tid;
        if (t < 2 * D * D) {
            int col = t & 127, k = t >> 7;
            WT[col * 256 + k] = f2bf(W[k * D + col]);
        }
    } else {
        int hb = blk - XB - WB;
        for (int i = tid; i < NBMAX; i += 256) h[i] = 0;
        __syncthreads();
        for (int i = hb * 256 + tid; i < E; i += HB * 256)
            atomicAdd(&h[edst[i] >> 7], 1);
        __syncthreads();
        for (int i = tid; i < NBMAX; i += 256) hpart[hb * NBMAX + i] = h[i];
    }
}

// sum 128 partials + exclusive scan of 1024 coarse counts (4/thread, 1 block)
__global__ __launch_bounds__(256) void cscan_kernel(const int* __restrict__ hpart,
                                                    int* __restrict__ ccnt,
                                                    int* __restrict__ cbase,
                                                    int* __restrict__ ccur) {
    __shared__ int p[256];
    int t = threadIdx.x;
    int s0 = 0, s1 = 0, s2 = 0, s3 = 0;
    for (int j = 0; j < HB; ++j) {
        int4 v = *(const int4*)(hpart + j * NBMAX + t * 4);
        s0 += v.x; s1 += v.y; s2 += v.z; s3 += v.w;
    }
    int loc = s0 + s1 + s2 + s3;
    p[t] = loc;
    __syncthreads();
    for (int off = 1; off < 256; off <<= 1) {
        int v = p[t];
        int u = (t >= off) ? p[t - off] : 0;
        __syncthreads();
        p[t] = v + u;
        __syncthreads();
    }
    int ex = p[t] - loc;
    ccnt[4 * t] = s0; ccnt[4 * t + 1] = s1; ccnt[4 * t + 2] = s2; ccnt[4 * t + 3] = s3;
    cbase[4 * t] = ex;            ccur[4 * t] = ex;
    cbase[4 * t + 1] = ex + s0;   ccur[4 * t + 1] = ex + s0;
    cbase[4 * t + 2] = ex + s0 + s1;      ccur[4 * t + 2] = ex + s0 + s1;
    cbase[4 * t + 3] = ex + s0 + s1 + s2; ccur[4 * t + 3] = ex + s0 + s1 + s2;
}

// LDS counting sort of a 2048-edge chunk into contiguous per-bin runs.
// bin = dst >> 7. pack.x = (src << 8) | (dst & 127), pack.y = fp32 val bits.
__global__ __launch_bounds__(256) void cfill_kernel(const int* __restrict__ esrc,
                                                    const int* __restrict__ edst,
                                                    const float* __restrict__ eval,
                                                    int* __restrict__ ccur,
                                                    int2* __restrict__ ep, int E) {
    __shared__ int lh[NBMAX];      // counts -> gdelta
    __shared__ int lcur[NBMAX];    // exclusive starts -> bump cursors
    __shared__ int p[256];
    __shared__ int2 ord[CHUNK];
    __shared__ unsigned short obk[CHUNK];

    const int tid = threadIdx.x;
    const int base = blockIdx.x * CHUNK;
    const int n = min(CHUNK, E - base);

    for (int i = tid; i < NBMAX; i += 256) lh[i] = 0;
    __syncthreads();

    int esv[8]; int ebk[8];
    float evv[8];
#pragma unroll
    for (int k = 0; k < 8; ++k) {
        int li = k * 256 + tid;
        if (li < n) {
            int i = base + li;
            int dst = edst[i];
            esv[k] = esrc[i];
            evv[k] = eval[i];
            int b = dst >> 7;
            ebk[k] = b | ((dst & 127) << 16);
            atomicAdd(&lh[b], 1);
        } else ebk[k] = -1;
    }
    __syncthreads();

    int s0 = lh[4 * tid], s1 = lh[4 * tid + 1], s2 = lh[4 * tid + 2], s3 = lh[4 * tid + 3];
    int loc = s0 + s1 + s2 + s3;
    p[tid] = loc;
    __syncthreads();
    for (int off = 1; off < 256; off <<= 1) {
        int v = p[tid];
        int u = (tid >= off) ? p[tid - off] : 0;
        __syncthreads();
        p[tid] = v + u;
        __syncthreads();
    }
    int ex = p[tid] - loc;
    lcur[4 * tid] = ex;
    lcur[4 * tid + 1] = ex + s0;
    lcur[4 * tid + 2] = ex + s0 + s1;
    lcur[4 * tid + 3] = ex + s0 + s1 + s2;
    __syncthreads();

#pragma unroll
    for (int k = 0; k < 8; ++k) {
        if (ebk[k] >= 0) {
            int b = ebk[k] & 0xffff, nl = ebk[k] >> 16;
            int slot = atomicAdd(&lcur[b], 1);
            ord[slot] = make_int2((esv[k] << 8) | nl, __builtin_bit_cast(int, evv[k]));
            obk[slot] = (unsigned short)b;
        }
    }
    __syncthreads();

    for (int b = tid; b < NBIN; b += 256) {
        int c = lh[b];
        if (c) lh[b] = atomicAdd(&ccur[b], c) - (lcur[b] - c);
    }
    __syncthreads();

    for (int i = tid; i < n; i += 256) {
        int b = obk[i];
        ep[lh[b] + i] = ord[i];
    }
}

// Fused sort+gather+GEMM. One block per 128-node bin, 512 threads (8 waves).
// Stage bin's edges in registers, LDS hist+scan over 128 nodes, scatter into
// LDS ord[] (never back to global). Wave w walks nodes [w*16,w*16+16) as one
// contiguous LDS run (R3's proven walk), flushes bf16 accb rows. Then 8-wave
// 128x128 MFMA GEMM: out = [x | accb] @ W + b.
__global__ __launch_bounds__(512, 4) void sg_kernel(
        const unsigned short* __restrict__ x_bf,
        const int* __restrict__ cbase,
        const int* __restrict__ ccnt,
        const int2* __restrict__ ep,
        const unsigned short* __restrict__ WT,
        const float* __restrict__ bias,
        float* __restrict__ out, int N) {
    __shared__ int2 ord[ORDCAP];                   // 24576 B
    __shared__ unsigned short accb[BNODES * 136];  // 34816 B
    __shared__ int h[BNODES];                      // counts -> cursors
    __shared__ int p[BNODES];
    __shared__ int nb[BNODES + 1];

    const int t = threadIdx.x;
    const int bin = blockIdx.x;
    const int cb = cbase[bin];
    const int n = ccnt[bin];
    const int node0 = bin * BNODES;
    const int w = t >> 6, lane = t & 63;
    unsigned int* accw = (unsigned int*)accb;

    for (int i = t * 8; i < BNODES * 136; i += 4096)
        *(uint4*)(accb + i) = make_uint4(0u, 0u, 0u, 0u);
    if (t < BNODES) h[t] = 0;
    __syncthreads();

    int2 ev[SCAP];
#pragma unroll
    for (int k = 0; k < SCAP; ++k) {
        int idx = k * 512 + t;
        if (idx < n) {
            ev[k] = ep[cb + idx];
            atomicAdd(&h[ev[k].x & 255], 1);
        } else ev[k] = make_int2(-1, 0);
    }
    __syncthreads();

    int c = 0;
    if (t < BNODES) { c = h[t]; p[t] = c; }
    __syncthreads();
    for (int off = 1; off < BNODES; off <<= 1) {
        int v = 0, u = 0;
        if (t < BNODES) { v = p[t]; u = (t >= off) ? p[t - off] : 0; }
        __syncthreads();
        if (t < BNODES) p[t] = v + u;
        __syncthreads();
    }
    if (t < BNODES) { int st = p[t] - c; nb[t] = st; h[t] = st; }
    if (t == 0) nb[BNODES] = n;
    __syncthreads();

#pragma unroll
    for (int k = 0; k < SCAP; ++k) {
        if (ev[k].x >= 0) {
            int nl = ev[k].x & 255;
            int pos = atomicAdd(&h[nl], 1);
            ord[pos] = ev[k];
        }
    }
    __syncthreads();

    // ---- walk: wave w owns nodes [w*16, w*16+16), contiguous in ord ----
    const int js = __builtin_amdgcn_readfirstlane(nb[w * 16]);
    const int je = __builtin_amdgcn_readfirstlane(nb[w * 16 + 16]);

    int cur = -1;
    float ax = 0.f, ay = 0.f;
    for (int g = js; g < je; g += 16) {
        int m = je - g; if (m > 16) m = 16;
        int2 e[16];
#pragma unroll
        for (int k = 0; k < 16; ++k) {
            int idx = g + k; if (idx >= je) idx = je - 1;
            e[k] = ord[idx];
        }
        unsigned int px[16];
#pragma unroll
        for (int k = 0; k < 16; ++k) {
            int sx = __builtin_amdgcn_readfirstlane(e[k].x);
            px[k] = *(const unsigned int*)(x_bf + ((sx >> 8) << 7) + lane * 2);
        }
#pragma unroll
        for (int k = 0; k < 16; ++k) {
            if (k < m) {
                int nd = e[k].x & 255;
                if (nd != cur) {
                    if (cur >= 0)
                        accw[cur * 68 + lane] =
                            (unsigned int)f2bf(ax) | ((unsigned int)f2bf(ay) << 16);
                    cur = nd; ax = 0.f; ay = 0.f;
                }
                float v = __builtin_bit_cast(float, e[k].y);
                ax += bf2f(px[k] & 0xffffu) * v;
                ay += bf2f(px[k] >> 16) * v;
            }
        }
    }
    if (cur >= 0)
        accw[cur * 68 + lane] = (unsigned int)f2bf(ax) | ((unsigned int)f2bf(ay) << 16);
    __syncthreads();

    // ---- GEMM: 8 waves tile 128 rows x 128 cols (wave = 32 rows x 64 cols) ----
    const int quad = lane >> 4;
    const int l15  = lane & 15;
    const int wr = w & 3, wc = w >> 2;

    f32x4 acc[2][4];
#pragma unroll
    for (int rt = 0; rt < 2; ++rt)
#pragma unroll
        for (int ct = 0; ct < 4; ++ct)
            acc[rt][ct] = (f32x4){0.f, 0.f, 0.f, 0.f};

#pragma unroll
    for (int ks = 0; ks < 8; ++ks) {
        bf16x8 wf[4];
#pragma unroll
        for (int ct = 0; ct < 4; ++ct)
            wf[ct] = *(const bf16x8*)(WT + (size_t)(wc * 64 + ct * 16 + l15) * 256 + ks * 32 + quad * 8);
#pragma unroll
        for (int rt = 0; rt < 2; ++rt) {
            int row = wr * 32 + rt * 16 + l15;
            bf16x8 a;
            if (ks < 4) {
                int rg = node0 + row; if (rg >= N) rg = N - 1;   // garbage rows unused
                a = *(const bf16x8*)(x_bf + (size_t)rg * D + ks * 32 + quad * 8);
            } else {
                a = *(const bf16x8*)(accb + row * 136 + (ks - 4) * 32 + quad * 8);
            }
#pragma unroll
            for (int ct = 0; ct < 4; ++ct)
                acc[rt][ct] = __builtin_amdgcn_mfma_f32_16x16x32_bf16(a, wf[ct], acc[rt][ct], 0, 0, 0);
        }
    }

#pragma unroll
    for (int ct = 0; ct < 4; ++ct) {
        int col = wc * 64 + ct * 16 + l15;
        float bv = bias[col];
#pragma unroll
        for (int rt = 0; rt < 2; ++rt) {
#pragma unroll
            for (int rg = 0; rg < 4; ++rg) {
                int row = node0 + wr * 32 + rt * 16 + quad * 4 + rg;
                if (row < N)
                    out[(size_t)row * D + col] = acc[rt][ct][rg] + bv;
            }
        }
    }
}

extern "C" void kernel_launch(void* const* d_in, const int* in_sizes, int n_in,
                              void* d_out, int out_size, void* d_ws, size_t ws_size,
                              hipStream_t stream) {
    const float* x    = (const float*)d_in[0];
    const int*   esrc = (const int*)d_in[1];
    const int*   edst = (const int*)d_in[2];
    const float* eval = (const float*)d_in[3];
    const float* W    = (const float*)d_in[4];
    const float* bias = (const float*)d_in[5];
    float*       out  = (float*)d_out;

    const int N  = in_sizes[0] / D;       // 100000
    const int E  = in_sizes[1];           // 1600000

    // ws layout (bytes)
    char* ws = (char*)d_ws;
    unsigned short* x_bf  = (unsigned short*)ws;               // 25,600,000
    int2*           ep    = (int2*)(ws + 25600000);            // 12,800,000
    unsigned short* WT    = (unsigned short*)(ws + 38400000);  // 65,536
    int*            ccnt  = (int*)(ws + 38465536);             // 4096
    int*            cbase = (int*)(ws + 38469632);             // 4096
    int*            ccur  = (int*)(ws + 38473728);             // 4096
    int*            hpart = (int*)(ws + 38477824);             // 524,288 (HB*1024*4)

    const int n4 = N * D / 4;
    const int XB = (n4 + 255) / 256;          // 12500
    const int WB = (2 * D * D + 255) / 256;   // 128

    prep_kernel<<<XB + WB + HB, 256, 0, stream>>>(x, x_bf, W, WT, edst, hpart,
                                                  n4, XB, WB, E);
    cscan_kernel<<<1, 256, 0, stream>>>(hpart, ccnt, cbase, ccur);
    cfill_kernel<<<(E + CHUNK - 1) / CHUNK, 256, 0, stream>>>(esrc, edst, eval,
                                                              ccur, ep, E);
    sg_kernel<<<NBIN, 512, 0, stream>>>(x_bf, cbase, ccnt, ep, WT, bias, out, N);
    (void)ws_size; (void)n_in; (void)out_size;
}

// Round 6
// 283.830 us; speedup vs baseline: 1.0069x; 1.0069x over previous
//
#include <hip/hip_runtime.h>

#define D 128
#define BN 64            // nodes per gather block
#define NBIN 391         // coarse bins of 256 nodes (100000/256 -> 391)
#define NBMAX 512
#define CHUNK 2048       // edges per cfill chunk
#define SCAP 12          // csort: staged edges per thread (12*512=6144 cap)

typedef __attribute__((ext_vector_type(8))) short bf16x8;
typedef __attribute__((ext_vector_type(4))) float f32x4;

__device__ __forceinline__ unsigned short f2bf(float f) {
    unsigned int u = __builtin_bit_cast(unsigned int, f);
    u = (u + 0x7fffu + ((u >> 16) & 1u)) >> 16;
    return (unsigned short)u;
}
__device__ __forceinline__ float bf2f(unsigned int u) {
    return __builtin_bit_cast(float, u << 16);
}

// Fused prep: x fp32->bf16, W transpose->bf16, zero coarse counters.
__global__ void prep_kernel(const float* __restrict__ x,
                            unsigned short* __restrict__ x_bf,
                            const float* __restrict__ W,
                            unsigned short* __restrict__ WT,
                            int* __restrict__ ccnt,
                            int n4, int XB, int WB) {
    int blk = blockIdx.x, tid = threadIdx.x;
    if (blk < XB) {
        int i = blk * 256 + tid;
        if (i < n4) {
            float4 v = ((const float4*)x)[i];
            ushort4 s;
            s.x = f2bf(v.x); s.y = f2bf(v.y); s.z = f2bf(v.z); s.w = f2bf(v.w);
            ((ushort4*)x_bf)[i] = s;
        }
    } else if (blk < XB + WB) {
        int t = (blk - XB) * 256 + tid;
        if (t < 2 * D * D) {
            int col = t & 127, k = t >> 7;
            WT[col * 256 + k] = f2bf(W[k * D + col]);
        }
    } else {
        ccnt[tid] = 0;
        ccnt[tid + 256] = 0;
    }
}

// coarse histogram, LDS-merged (bin = dst >> 8)
__global__ __launch_bounds__(256) void chist_kernel(const int* __restrict__ edst,
                                                    int* __restrict__ ccnt, int E) {
    __shared__ int h[NBMAX];
    for (int i = threadIdx.x; i < NBMAX; i += 256) h[i] = 0;
    __syncthreads();
    int stride = gridDim.x * 256;
    for (int e = blockIdx.x * 256 + threadIdx.x; e < E; e += stride)
        atomicAdd(&h[edst[e] >> 8], 1);
    __syncthreads();
    for (int i = threadIdx.x; i < NBIN; i += 256) {
        int c = h[i];
        if (c) atomicAdd(&ccnt[i], c);
    }
}

// single-block exclusive scan of 512 coarse counts (2/thread)
__global__ __launch_bounds__(256) void cscan_kernel(const int* __restrict__ ccnt,
                                                    int* __restrict__ cbase,
                                                    int* __restrict__ ccur) {
    __shared__ int p[256];
    int t = threadIdx.x;
    int s0 = ccnt[2 * t], s1 = ccnt[2 * t + 1];
    int loc = s0 + s1;
    p[t] = loc;
    __syncthreads();
    for (int off = 1; off < 256; off <<= 1) {
        int v = p[t];
        int u = (t >= off) ? p[t - off] : 0;
        __syncthreads();
        p[t] = v + u;
        __syncthreads();
    }
    int ex = p[t] - loc;
    cbase[2 * t] = ex;     ccur[2 * t] = ex;
    cbase[2 * t + 1] = ex + s0; ccur[2 * t + 1] = ex + s0;
}

// LDS counting sort of a 2048-edge chunk into contiguous per-coarse-bin runs.
// pack.x = (src << 8) | (dst & 255), pack.y = fp32 val bits.
__global__ __launch_bounds__(256) void cfill_kernel(const int* __restrict__ esrc,
                                                    const int* __restrict__ edst,
                                                    const float* __restrict__ eval,
                                                    int* __restrict__ ccur,
                                                    int2* __restrict__ ep, int E) {
    __shared__ int lh[NBMAX];      // counts -> gdelta
    __shared__ int lcur[NBMAX];    // exclusive starts -> bump cursors
    __shared__ int p[256];
    __shared__ int2 ord[CHUNK];
    __shared__ unsigned short obk[CHUNK];

    const int tid = threadIdx.x;
    const int base = blockIdx.x * CHUNK;
    const int n = min(CHUNK, E - base);

    for (int i = tid; i < NBMAX; i += 256) lh[i] = 0;
    __syncthreads();

    int esv[8]; int ebk[8];
    float evv[8];
#pragma unroll
    for (int k = 0; k < 8; ++k) {
        int li = k * 256 + tid;
        if (li < n) {
            int i = base + li;
            int dst = edst[i];
            esv[k] = esrc[i];
            evv[k] = eval[i];
            int b = dst >> 8;
            ebk[k] = b | ((dst & 255) << 16);
            atomicAdd(&lh[b], 1);
        } else ebk[k] = -1;
    }
    __syncthreads();

    int s0 = lh[2 * tid], s1 = lh[2 * tid + 1];
    int loc = s0 + s1;
    p[tid] = loc;
    __syncthreads();
    for (int off = 1; off < 256; off <<= 1) {
        int v = p[tid];
        int u = (tid >= off) ? p[tid - off] : 0;
        __syncthreads();
        p[tid] = v + u;
        __syncthreads();
    }
    int ex = p[tid] - loc;
    lcur[2 * tid] = ex;
    lcur[2 * tid + 1] = ex + s0;
    __syncthreads();

#pragma unroll
    for (int k = 0; k < 8; ++k) {
        if (ebk[k] >= 0) {
            int b = ebk[k] & 0xffff, nl = ebk[k] >> 16;
            int slot = atomicAdd(&lcur[b], 1);
            ord[slot] = make_int2((esv[k] << 8) | nl, __builtin_bit_cast(int, evv[k]));
            obk[slot] = (unsigned short)b;
        }
    }
    __syncthreads();

    for (int b = tid; b < NBIN; b += 256) {
        int c = lh[b];
        if (c) lh[b] = atomicAdd(&ccur[b], c) - (lcur[b] - c);
    }
    __syncthreads();

    for (int i = tid; i < n; i += 256) {
        int b = obk[i];
        ep[lh[b] + i] = ord[i];
    }
}

// One block per coarse bin: stage bin's edges in registers, LDS node histogram
// + scan (emits node_start), then in-place scatter to full CSR order within the
// bin's L2-resident range. No global atomics.
__global__ __launch_bounds__(512) void csort_kernel(int2* __restrict__ ep,
                                                    const int* __restrict__ cbase,
                                                    const int* __restrict__ ccnt,
                                                    int* __restrict__ node_start) {
    __shared__ int h[256];   // counts -> cursors
    __shared__ int p[256];

    const int t = threadIdx.x;
    const int bin = blockIdx.x;
    const int cb = cbase[bin];
    const int ce = cb + ccnt[bin];

    if (t < 256) h[t] = 0;
    __syncthreads();

    int2 ev[SCAP];
#pragma unroll
    for (int k = 0; k < SCAP; ++k) {
        int idx = cb + k * 512 + t;
        if (idx < ce) {
            int2 e = ep[idx];
            ev[k] = e;
            atomicAdd(&h[e.x & 255], 1);
        } else ev[k] = make_int2(-1, 0);
    }
    __syncthreads();

    int c = 0;
    if (t < 256) { c = h[t]; p[t] = c; }
    __syncthreads();
    for (int off = 1; off < 256; off <<= 1) {
        int v = 0, u = 0;
        if (t < 256) { v = p[t]; u = (t >= off) ? p[t - off] : 0; }
        __syncthreads();
        if (t < 256) p[t] = v + u;
        __syncthreads();
    }
    if (t < 256) {
        int st = cb + p[t] - c;
        node_start[bin * 256 + t] = st;
        h[t] = st;
    }
    __syncthreads();

#pragma unroll
    for (int k = 0; k < SCAP; ++k) {
        if (ev[k].x >= 0) {
            int nl = ev[k].x & 255;
            int pos = atomicAdd(&h[nl], 1);
            ep[pos] = make_int2(ev[k].x & 0xFFFFFF3F, ev[k].y);
        }
    }
}

// One block per 64-node bucket, 512 threads (8 waves). Wave w owns nodes
// [w*8, w*8+8): one contiguous CSR edge range -> wave-uniform edge batches,
// fp32 register accumulation, one bf16 flush per node. 8 waves/block raises
// the occupancy ceiling to 32 waves/CU (grid 1563 ~ 6 blocks/CU; 4 resident
// blocks saturate). LDS = accb tile only (17.4 KB -> 9 blocks fit).
__global__ __launch_bounds__(512, 8) void gather_fused_kernel(
        const unsigned short* __restrict__ x_bf,
        const int* __restrict__ node_start,
        const int2* __restrict__ edge_pack,
        const unsigned short* __restrict__ WT,
        const float* __restrict__ bias,
        float* __restrict__ out, int N) {
    __shared__ unsigned short accb[BN * 136];   // bf16 accum tile, 17408 B
    __shared__ int nb[BN + 1];

    const int tid = threadIdx.x;
    const int node0 = blockIdx.x * BN;
    const int w = tid >> 6, lane = tid & 63;
    unsigned int* accw = (unsigned int*)accb;   // word l of row r = feats 2l,2l+1

    for (int i = tid * 8; i < BN * 136; i += 4096)
        *(uint4*)(accb + i) = make_uint4(0u, 0u, 0u, 0u);
    if (tid <= BN) nb[tid] = node_start[node0 + tid];
    __syncthreads();

    const int js = __builtin_amdgcn_readfirstlane(nb[w * 8]);
    const int je = __builtin_amdgcn_readfirstlane(nb[w * 8 + 8]);
    const unsigned short* xl = x_bf + lane * 2;

    int cur = -1;
    float ax = 0.f, ay = 0.f;
    for (int g = js; g < je; g += 16) {
        int m = je - g; if (m > 16) m = 16;
        int2 e[16];
#pragma unroll
        for (int k = 0; k < 16; ++k) {
            int idx = g + k; if (idx >= je) idx = je - 1;
            e[k] = edge_pack[idx];
        }
        unsigned int p[16];
#pragma unroll
        for (int k = 0; k < 16; ++k)
            p[k] = *(const unsigned int*)(xl + ((e[k].x >> 8) << 7));
#pragma unroll
        for (int k = 0; k < 16; ++k) {
            if (k < m) {
                int nd = e[k].x & 63;
                if (nd != cur) {
                    if (cur >= 0)
                        accw[cur * 68 + lane] =
                            (unsigned int)f2bf(ax) | ((unsigned int)f2bf(ay) << 16);
                    cur = nd; ax = 0.f; ay = 0.f;
                }
                float v = __builtin_bit_cast(float, e[k].y);
                ax += bf2f(p[k] & 0xffffu) * v;
                ay += bf2f(p[k] >> 16) * v;
            }
        }
    }
    if (cur >= 0)
        accw[cur * 68 + lane] = (unsigned int)f2bf(ax) | ((unsigned int)f2bf(ay) << 16);
    __syncthreads();

    // ---- fused GEMM: out[node0..node0+64) = [x | accb] @ W + b ----
    // 8 waves tile 64 rows x 128 cols: wave = 16 rows (wr=w&3) x 64 cols (wc=w>>2)
    const int quad = lane >> 4;
    const int l15  = lane & 15;
    const int wr = w & 3, wc = w >> 2;

    f32x4 acc[4];
#pragma unroll
    for (int ct = 0; ct < 4; ++ct)
        acc[ct] = (f32x4){0.f, 0.f, 0.f, 0.f};

#pragma unroll
    for (int ks = 0; ks < 8; ++ks) {
        bf16x8 a;
        int row = wr * 16 + l15;
        if (ks < 4) {
            int rg = node0 + row; if (rg >= N) rg = N - 1;   // garbage rows unused
            a = *(const bf16x8*)(x_bf + (size_t)rg * D + ks * 32 + quad * 8);
        } else {
            a = *(const bf16x8*)(accb + row * 136 + (ks - 4) * 32 + quad * 8);
        }
#pragma unroll
        for (int ct = 0; ct < 4; ++ct) {
            bf16x8 wf = *(const bf16x8*)(WT + (size_t)(wc * 64 + ct * 16 + l15) * 256 + ks * 32 + quad * 8);
            acc[ct] = __builtin_amdgcn_mfma_f32_16x16x32_bf16(a, wf, acc[ct], 0, 0, 0);
        }
    }

#pragma unroll
    for (int ct = 0; ct < 4; ++ct) {
        int col = wc * 64 + ct * 16 + l15;
        float bv = bias[col];
#pragma unroll
        for (int rg = 0; rg < 4; ++rg) {
            int row = node0 + wr * 16 + quad * 4 + rg;
            if (row < N)
                out[(size_t)row * D + col] = acc[ct][rg] + bv;
        }
    }
}

extern "C" void kernel_launch(void* const* d_in, const int* in_sizes, int n_in,
                              void* d_out, int out_size, void* d_ws, size_t ws_size,
                              hipStream_t stream) {
    const float* x    = (const float*)d_in[0];
    const int*   esrc = (const int*)d_in[1];
    const int*   edst = (const int*)d_in[2];
    const float* eval = (const float*)d_in[3];
    const float* W    = (const float*)d_in[4];
    const float* bias = (const float*)d_in[5];
    float*       out  = (float*)d_out;

    const int N  = in_sizes[0] / D;       // 100000
    const int E  = in_sizes[1];           // 1600000
    const int NG = (N + BN - 1) / BN;     // 1563 gather blocks

    // ws layout (bytes)
    char* ws = (char*)d_ws;
    unsigned short* x_bf  = (unsigned short*)ws;               // 25,600,000
    int2*           ep    = (int2*)(ws + 25600000);            // 12,800,000
    unsigned short* WT    = (unsigned short*)(ws + 38400000);  // 65,536
    int*            nbg   = (int*)(ws + 38465536);             // 400,384 (NBIN*256*4)
    int*            ccnt  = (int*)(ws + 38865920);             // 2048
    int*            cbase = (int*)(ws + 38867968);             // 2048
    int*            ccur  = (int*)(ws + 38870016);             // 2048

    const int n4 = N * D / 4;
    const int XB = (n4 + 255) / 256;          // 12500
    const int WB = (2 * D * D + 255) / 256;   // 128

    prep_kernel<<<XB + WB + 1, 256, 0, stream>>>(x, x_bf, W, WT, ccnt, n4, XB, WB);
    chist_kernel<<<512, 256, 0, stream>>>(edst, ccnt, E);
    cscan_kernel<<<1, 256, 0, stream>>>(ccnt, cbase, ccur);
    cfill_kernel<<<(E + CHUNK - 1) / CHUNK, 256, 0, stream>>>(esrc, edst, eval,
                                                              ccur, ep, E);
    csort_kernel<<<NBIN, 512, 0, stream>>>(ep, cbase, ccnt, nbg);
    gather_fused_kernel<<<NG, 512, 0, stream>>>(x_bf, nbg, ep, WT, bias, out, N);
    (void)ws_size; (void)n_in; (void)out_size;
}

// Round 7
// 274.488 us; speedup vs baseline: 1.0412x; 1.0340x over previous
//
#include <hip/hip_runtime.h>

#define D 128
#define BN 64            // nodes per gather block
#define NBIN 391         // coarse bins of 256 nodes (100000/256 -> 391)
#define NBMAX 512
#define CHUNK 2048       // edges per cfill chunk
#define SCAP 12          // csort: staged edges per thread (12*512=6144 cap)

typedef __attribute__((ext_vector_type(8))) short bf16x8;
typedef __attribute__((ext_vector_type(4))) float f32x4;

__device__ __forceinline__ unsigned short f2bf(float f) {
    unsigned int u = __builtin_bit_cast(unsigned int, f);
    u = (u + 0x7fffu + ((u >> 16) & 1u)) >> 16;
    return (unsigned short)u;
}
__device__ __forceinline__ float bf2f(unsigned int u) {
    return __builtin_bit_cast(float, u << 16);
}

// Fused prep: x fp32->bf16, W transpose->bf16, zero coarse counters.
__global__ void prep_kernel(const float* __restrict__ x,
                            unsigned short* __restrict__ x_bf,
                            const float* __restrict__ W,
                            unsigned short* __restrict__ WT,
                            int* __restrict__ ccnt,
                            int n4, int XB, int WB) {
    int blk = blockIdx.x, tid = threadIdx.x;
    if (blk < XB) {
        int i = blk * 256 + tid;
        if (i < n4) {
            float4 v = ((const float4*)x)[i];
            ushort4 s;
            s.x = f2bf(v.x); s.y = f2bf(v.y); s.z = f2bf(v.z); s.w = f2bf(v.w);
            ((ushort4*)x_bf)[i] = s;
        }
    } else if (blk < XB + WB) {
        int t = (blk - XB) * 256 + tid;
        if (t < 2 * D * D) {
            int col = t & 127, k = t >> 7;
            WT[col * 256 + k] = f2bf(W[k * D + col]);
        }
    } else {
        ccnt[tid] = 0;
        ccnt[tid + 256] = 0;
    }
}

// coarse histogram, LDS-merged (bin = dst >> 8)
__global__ __launch_bounds__(256) void chist_kernel(const int* __restrict__ edst,
                                                    int* __restrict__ ccnt, int E) {
    __shared__ int h[NBMAX];
    for (int i = threadIdx.x; i < NBMAX; i += 256) h[i] = 0;
    __syncthreads();
    int stride = gridDim.x * 256;
    for (int e = blockIdx.x * 256 + threadIdx.x; e < E; e += stride)
        atomicAdd(&h[edst[e] >> 8], 1);
    __syncthreads();
    for (int i = threadIdx.x; i < NBIN; i += 256) {
        int c = h[i];
        if (c) atomicAdd(&ccnt[i], c);
    }
}

// single-block exclusive scan of 512 coarse counts (2/thread)
__global__ __launch_bounds__(256) void cscan_kernel(const int* __restrict__ ccnt,
                                                    int* __restrict__ cbase,
                                                    int* __restrict__ ccur) {
    __shared__ int p[256];
    int t = threadIdx.x;
    int s0 = ccnt[2 * t], s1 = ccnt[2 * t + 1];
    int loc = s0 + s1;
    p[t] = loc;
    __syncthreads();
    for (int off = 1; off < 256; off <<= 1) {
        int v = p[t];
        int u = (t >= off) ? p[t - off] : 0;
        __syncthreads();
        p[t] = v + u;
        __syncthreads();
    }
    int ex = p[t] - loc;
    cbase[2 * t] = ex;     ccur[2 * t] = ex;
    cbase[2 * t + 1] = ex + s0; ccur[2 * t + 1] = ex + s0;
}

// LDS counting sort of a 2048-edge chunk into contiguous per-coarse-bin runs.
// pack.x = (src << 8) | (dst & 255), pack.y = fp32 val bits.
__global__ __launch_bounds__(256) void cfill_kernel(const int* __restrict__ esrc,
                                                    const int* __restrict__ edst,
                                                    const float* __restrict__ eval,
                                                    int* __restrict__ ccur,
                                                    int2* __restrict__ ep, int E) {
    __shared__ int lh[NBMAX];      // counts -> gdelta
    __shared__ int lcur[NBMAX];    // exclusive starts -> bump cursors
    __shared__ int p[256];
    __shared__ int2 ord[CHUNK];
    __shared__ unsigned short obk[CHUNK];

    const int tid = threadIdx.x;
    const int base = blockIdx.x * CHUNK;
    const int n = min(CHUNK, E - base);

    for (int i = tid; i < NBMAX; i += 256) lh[i] = 0;
    __syncthreads();

    int esv[8]; int ebk[8];
    float evv[8];
#pragma unroll
    for (int k = 0; k < 8; ++k) {
        int li = k * 256 + tid;
        if (li < n) {
            int i = base + li;
            int dst = edst[i];
            esv[k] = esrc[i];
            evv[k] = eval[i];
            int b = dst >> 8;
            ebk[k] = b | ((dst & 255) << 16);
            atomicAdd(&lh[b], 1);
        } else ebk[k] = -1;
    }
    __syncthreads();

    int s0 = lh[2 * tid], s1 = lh[2 * tid + 1];
    int loc = s0 + s1;
    p[tid] = loc;
    __syncthreads();
    for (int off = 1; off < 256; off <<= 1) {
        int v = p[tid];
        int u = (tid >= off) ? p[tid - off] : 0;
        __syncthreads();
        p[tid] = v + u;
        __syncthreads();
    }
    int ex = p[tid] - loc;
    lcur[2 * tid] = ex;
    lcur[2 * tid + 1] = ex + s0;
    __syncthreads();

#pragma unroll
    for (int k = 0; k < 8; ++k) {
        if (ebk[k] >= 0) {
            int b = ebk[k] & 0xffff, nl = ebk[k] >> 16;
            int slot = atomicAdd(&lcur[b], 1);
            ord[slot] = make_int2((esv[k] << 8) | nl, __builtin_bit_cast(int, evv[k]));
            obk[slot] = (unsigned short)b;
        }
    }
    __syncthreads();

    for (int b = tid; b < NBIN; b += 256) {
        int c = lh[b];
        if (c) lh[b] = atomicAdd(&ccur[b], c) - (lcur[b] - c);
    }
    __syncthreads();

    for (int i = tid; i < n; i += 256) {
        int b = obk[i];
        ep[lh[b] + i] = ord[i];
    }
}

// One block per coarse bin: stage bin's edges in registers, LDS node histogram
// + scan (emits node_start), then in-place scatter to full CSR order within the
// bin's L2-resident range. No global atomics.
__global__ __launch_bounds__(512) void csort_kernel(int2* __restrict__ ep,
                                                    const int* __restrict__ cbase,
                                                    const int* __restrict__ ccnt,
                                                    int* __restrict__ node_start) {
    __shared__ int h[256];   // counts -> cursors
    __shared__ int p[256];

    const int t = threadIdx.x;
    const int bin = blockIdx.x;
    const int cb = cbase[bin];
    const int ce = cb + ccnt[bin];

    if (t < 256) h[t] = 0;
    __syncthreads();

    int2 ev[SCAP];
#pragma unroll
    for (int k = 0; k < SCAP; ++k) {
        int idx = cb + k * 512 + t;
        if (idx < ce) {
            int2 e = ep[idx];
            ev[k] = e;
            atomicAdd(&h[e.x & 255], 1);
        } else ev[k] = make_int2(-1, 0);
    }
    __syncthreads();

    int c = 0;
    if (t < 256) { c = h[t]; p[t] = c; }
    __syncthreads();
    for (int off = 1; off < 256; off <<= 1) {
        int v = 0, u = 0;
        if (t < 256) { v = p[t]; u = (t >= off) ? p[t - off] : 0; }
        __syncthreads();
        if (t < 256) p[t] = v + u;
        __syncthreads();
    }
    if (t < 256) {
        int st = cb + p[t] - c;
        node_start[bin * 256 + t] = st;
        h[t] = st;
    }
    __syncthreads();

#pragma unroll
    for (int k = 0; k < SCAP; ++k) {
        if (ev[k].x >= 0) {
            int nl = ev[k].x & 255;
            int pos = atomicAdd(&h[nl], 1);
            ep[pos] = make_int2(ev[k].x & 0xFFFFFF3F, ev[k].y);
        }
    }
}

// One block per 64-node bucket, 256 threads (4 waves). Wave w owns nodes
// [w*16, w*16+16): one contiguous CSR edge range -> wave-uniform edge batches,
// fp32 register accumulation, one bf16 flush per node. launch_bounds (256,4)
// gives the allocator 128 VGPRs so the full 16-deep e[]+px[] batch stays live
// (at (256,8)/64-cap the compiler serialized the edge loads; VGPR_Count=32).
__global__ __launch_bounds__(256, 4) void gather_fused_kernel(
        const unsigned short* __restrict__ x_bf,
        const int* __restrict__ node_start,
        const int2* __restrict__ edge_pack,
        const unsigned short* __restrict__ WT,
        const float* __restrict__ bias,
        float* __restrict__ out, int N) {
    __shared__ unsigned short accb[BN * 136];   // bf16 accum tile, 17408 B
    __shared__ int nb[BN + 1];

    const int tid = threadIdx.x;
    const int node0 = blockIdx.x * BN;
    const int w = tid >> 6, lane = tid & 63;
    unsigned int* accw = (unsigned int*)accb;   // word l of row r = feats 2l,2l+1

    for (int i = tid * 8; i < BN * 136; i += 2048)
        *(uint4*)(accb + i) = make_uint4(0u, 0u, 0u, 0u);
    if (tid <= BN) nb[tid] = node_start[node0 + tid];
    __syncthreads();

    const int js = __builtin_amdgcn_readfirstlane(nb[w * 16]);
    const int je = __builtin_amdgcn_readfirstlane(nb[w * 16 + 16]);
    const unsigned short* xl = x_bf + lane * 2;

    int cur = -1;
    float ax = 0.f, ay = 0.f;
    for (int g = js; g < je; g += 16) {
        int m = je - g; if (m > 16) m = 16;
        int2 e[16];
#pragma unroll
        for (int k = 0; k < 16; ++k) {
            int idx = g + k; if (idx >= je) idx = je - 1;
            e[k] = edge_pack[idx];
        }
        unsigned int p[16];
#pragma unroll
        for (int k = 0; k < 16; ++k)
            p[k] = *(const unsigned int*)(xl + ((e[k].x >> 8) << 7));
#pragma unroll
        for (int k = 0; k < 16; ++k) {
            if (k < m) {
                int nd = e[k].x & 63;
                if (nd != cur) {
                    if (cur >= 0)
                        accw[cur * 68 + lane] =
                            (unsigned int)f2bf(ax) | ((unsigned int)f2bf(ay) << 16);
                    cur = nd; ax = 0.f; ay = 0.f;
                }
                float v = __builtin_bit_cast(float, e[k].y);
                ax += bf2f(p[k] & 0xffffu) * v;
                ay += bf2f(p[k] >> 16) * v;
            }
        }
    }
    if (cur >= 0)
        accw[cur * 68 + lane] = (unsigned int)f2bf(ax) | ((unsigned int)f2bf(ay) << 16);
    __syncthreads();

    // ---- fused GEMM phase: out[node0..node0+64) = [x | accb] @ W + b ----
    const int quad = lane >> 4;
    const int l15  = lane & 15;
    const int colbase = w * 32;

    f32x4 acc[4][2];
#pragma unroll
    for (int rt = 0; rt < 4; ++rt) {
        acc[rt][0] = (f32x4){0.f, 0.f, 0.f, 0.f};
        acc[rt][1] = (f32x4){0.f, 0.f, 0.f, 0.f};
    }

#pragma unroll
    for (int ks = 0; ks < 8; ++ks) {
        bf16x8 wf0 = *(const bf16x8*)(WT + (size_t)(colbase + l15) * 256 + ks * 32 + quad * 8);
        bf16x8 wf1 = *(const bf16x8*)(WT + (size_t)(colbase + 16 + l15) * 256 + ks * 32 + quad * 8);
#pragma unroll
        for (int rt = 0; rt < 4; ++rt) {
            int row = rt * 16 + l15;
            bf16x8 a;
            if (ks < 4) {
                int rg = node0 + row; if (rg >= N) rg = N - 1;   // garbage rows unused
                a = *(const bf16x8*)(x_bf + (size_t)rg * D + ks * 32 + quad * 8);
            } else {
                a = *(const bf16x8*)(accb + row * 136 + (ks - 4) * 32 + quad * 8);
            }
            acc[rt][0] = __builtin_amdgcn_mfma_f32_16x16x32_bf16(a, wf0, acc[rt][0], 0, 0, 0);
            acc[rt][1] = __builtin_amdgcn_mfma_f32_16x16x32_bf16(a, wf1, acc[rt][1], 0, 0, 0);
        }
    }

#pragma unroll
    for (int ct = 0; ct < 2; ++ct) {
        int col = colbase + ct * 16 + l15;
        float bv = bias[col];
#pragma unroll
        for (int rt = 0; rt < 4; ++rt) {
#pragma unroll
            for (int rg = 0; rg < 4; ++rg) {
                int row = node0 + rt * 16 + quad * 4 + rg;
                if (row < N)
                    out[(size_t)row * D + col] = acc[rt][ct][rg] + bv;
            }
        }
    }
}

extern "C" void kernel_launch(void* const* d_in, const int* in_sizes, int n_in,
                              void* d_out, int out_size, void* d_ws, size_t ws_size,
                              hipStream_t stream) {
    const float* x    = (const float*)d_in[0];
    const int*   esrc = (const int*)d_in[1];
    const int*   edst = (const int*)d_in[2];
    const float* eval = (const float*)d_in[3];
    const float* W    = (const float*)d_in[4];
    const float* bias = (const float*)d_in[5];
    float*       out  = (float*)d_out;

    const int N  = in_sizes[0] / D;       // 100000
    const int E  = in_sizes[1];           // 1600000
    const int NG = (N + BN - 1) / BN;     // 1563 gather blocks

    // ws layout (bytes)
    char* ws = (char*)d_ws;
    unsigned short* x_bf  = (unsigned short*)ws;               // 25,600,000
    int2*           ep    = (int2*)(ws + 25600000);            // 12,800,000
    unsigned short* WT    = (unsigned short*)(ws + 38400000);  // 65,536
    int*            nbg   = (int*)(ws + 38465536);             // 400,384 (NBIN*256*4)
    int*            ccnt  = (int*)(ws + 38865920);             // 2048
    int*            cbase = (int*)(ws + 38867968);             // 2048
    int*            ccur  = (int*)(ws + 38870016);             // 2048

    const int n4 = N * D / 4;
    const int XB = (n4 + 255) / 256;          // 12500
    const int WB = (2 * D * D + 255) / 256;   // 128

    prep_kernel<<<XB + WB + 1, 256, 0, stream>>>(x, x_bf, W, WT, ccnt, n4, XB, WB);
    chist_kernel<<<512, 256, 0, stream>>>(edst, ccnt, E);
    cscan_kernel<<<1, 256, 0, stream>>>(ccnt, cbase, ccur);
    cfill_kernel<<<(E + CHUNK - 1) / CHUNK, 256, 0, stream>>>(esrc, edst, eval,
                                                              ccur, ep, E);
    csort_kernel<<<NBIN, 512, 0, stream>>>(ep, cbase, ccnt, nbg);
    gather_fused_kernel<<<NG, 256, 0, stream>>>(x_bf, nbg, ep, WT, bias, out, N);
    (void)ws_size; (void)n_in; (void)out_size;
}

// Round 8
// 236.092 us; speedup vs baseline: 1.2105x; 1.1626x over previous
//
#include <hip/hip_runtime.h>

#define D 128
#define BN 64            // nodes per gather block
#define NBIN 391         // coarse bins of 256 nodes (100000/256 -> 391)
#define NBMAX 512
#define CHUNK 4096       // edges per hist/cfill chunk
#define SCAP 12          // csort: staged edges per thread (12*512=6144 cap)

typedef __attribute__((ext_vector_type(8))) short bf16x8;
typedef __attribute__((ext_vector_type(4))) float f32x4;

__device__ __forceinline__ unsigned short f2bf(float f) {
    unsigned int u = __builtin_bit_cast(unsigned int, f);
    u = (u + 0x7fffu + ((u >> 16) & 1u)) >> 16;
    return (unsigned short)u;
}
__device__ __forceinline__ float bf2f(unsigned int u) {
    return __builtin_bit_cast(float, u << 16);
}

// Fused prep: x fp32->bf16, W transpose->bf16.
__global__ void prep_kernel(const float* __restrict__ x,
                            unsigned short* __restrict__ x_bf,
                            const float* __restrict__ W,
                            unsigned short* __restrict__ WT,
                            int n4, int XB) {
    int blk = blockIdx.x, tid = threadIdx.x;
    if (blk < XB) {
        int i = blk * 256 + tid;
        if (i < n4) {
            float4 v = ((const float4*)x)[i];
            ushort4 s;
            s.x = f2bf(v.x); s.y = f2bf(v.y); s.z = f2bf(v.z); s.w = f2bf(v.w);
            ((ushort4*)x_bf)[i] = s;
        }
    } else {
        int t = (blk - XB) * 256 + tid;
        if (t < 2 * D * D) {
            int col = t & 127, k = t >> 7;
            WT[col * 256 + k] = f2bf(W[k * D + col]);
        }
    }
}

// per-chunk histogram: hcnt[c][b] = # edges of chunk c in bin b. No global atomics.
__global__ __launch_bounds__(512) void hist_kernel(const int* __restrict__ edst,
                                                   int* __restrict__ hcnt, int E) {
    __shared__ int h[NBMAX];
    const int t = threadIdx.x, c = blockIdx.x;
    h[t] = 0;
    __syncthreads();
    const int base = c * CHUNK;
    const int n = min(CHUNK, E - base);
#pragma unroll
    for (int k = 0; k < 8; ++k) {
        int li = k * 512 + t;
        if (li < n) atomicAdd(&h[edst[base + li] >> 8], 1);
    }
    __syncthreads();
    hcnt[c * NBMAX + t] = h[t];
}

// per-bin exclusive scan over chunks: cpos[b][c] = sum_{c'<c} hcnt[c'][b];
// ccnt[b] = bin total. One wave per bin (512 waves), shfl-scan, no atomics.
__global__ __launch_bounds__(256) void binscan_kernel(const int* __restrict__ hcnt,
                                                      int* __restrict__ cpos,
                                                      int* __restrict__ ccnt, int NCH) {
    const int tid = threadIdx.x;
    const int lane = tid & 63;
    const int b = blockIdx.x * 4 + (tid >> 6);   // 128 blocks x 4 waves = 512 bins
    int run = 0;
    for (int c0 = 0; c0 < NCH; c0 += 64) {
        int c = c0 + lane;
        int v = (c < NCH) ? hcnt[c * NBMAX + b] : 0;
        int s = v;
#pragma unroll
        for (int off = 1; off < 64; off <<= 1) {
            int u = __shfl_up(s, off, 64);
            if (lane >= off) s += u;
        }
        if (c < NCH) cpos[b * NCH + c] = run + s - v;
        run += __shfl(s, 63, 64);
    }
    if (lane == 0) ccnt[b] = run;
}

// single-block exclusive scan of 512 bin totals (2/thread)
__global__ __launch_bounds__(256) void cscan_kernel(const int* __restrict__ ccnt,
                                                    int* __restrict__ cbase) {
    __shared__ int p[256];
    int t = threadIdx.x;
    int s0 = ccnt[2 * t], s1 = ccnt[2 * t + 1];
    int loc = s0 + s1;
    p[t] = loc;
    __syncthreads();
    for (int off = 1; off < 256; off <<= 1) {
        int v = p[t];
        int u = (t >= off) ? p[t - off] : 0;
        __syncthreads();
        p[t] = v + u;
        __syncthreads();
    }
    int ex = p[t] - loc;
    cbase[2 * t] = ex;
    cbase[2 * t + 1] = ex + s0;
}

// LDS counting sort of a 4096-edge chunk into contiguous per-coarse-bin runs.
// Destination = cbase[b] + cpos[b][chunk] (deterministic, no global atomics).
// pack.x = (src << 8) | (dst & 255), pack.y = fp32 val bits.
__global__ __launch_bounds__(512) void cfill_kernel(const int* __restrict__ esrc,
                                                    const int* __restrict__ edst,
                                                    const float* __restrict__ eval,
                                                    const int* __restrict__ cbase,
                                                    const int* __restrict__ cpos,
                                                    int2* __restrict__ ep, int E, int NCH) {
    __shared__ int lh[NBMAX];      // counts -> gdelta
    __shared__ int lcur[NBMAX];    // exclusive starts -> bump cursors
    __shared__ int p[NBMAX];
    __shared__ int2 ord[CHUNK];
    __shared__ unsigned short obk[CHUNK];

    const int t = threadIdx.x;
    const int blk = blockIdx.x;
    const int base = blk * CHUNK;
    const int n = min(CHUNK, E - base);

    lh[t] = 0;
    __syncthreads();

    int esv[8]; int ebk[8];
    float evv[8];
#pragma unroll
    for (int k = 0; k < 8; ++k) {
        int li = k * 512 + t;
        if (li < n) {
            int i = base + li;
            int dst = edst[i];
            esv[k] = esrc[i];
            evv[k] = eval[i];
            int b = dst >> 8;
            ebk[k] = b | ((dst & 255) << 16);
            atomicAdd(&lh[b], 1);
        } else ebk[k] = -1;
    }
    __syncthreads();

    int cnt = lh[t];
    p[t] = cnt;
    __syncthreads();
    for (int off = 1; off < NBMAX; off <<= 1) {
        int v = p[t];
        int u = (t >= off) ? p[t - off] : 0;
        __syncthreads();
        p[t] = v + u;
        __syncthreads();
    }
    lcur[t] = p[t] - cnt;
    __syncthreads();

#pragma unroll
    for (int k = 0; k < 8; ++k) {
        if (ebk[k] >= 0) {
            int b = ebk[k] & 0xffff, nl = ebk[k] >> 16;
            int slot = atomicAdd(&lcur[b], 1);
            ord[slot] = make_int2((esv[k] << 8) | nl, __builtin_bit_cast(int, evv[k]));
            obk[slot] = (unsigned short)b;
        }
    }
    __syncthreads();

    if (t < NBIN) {
        int c2 = lh[t];
        if (c2) lh[t] = cbase[t] + cpos[t * NCH + blk] - (lcur[t] - c2);
    }
    __syncthreads();

    for (int i = t; i < n; i += 512) {
        int b = obk[i];
        ep[lh[b] + i] = ord[i];
    }
}

// One block per coarse bin: stage bin's edges in registers, LDS node histogram
// + scan (emits node_start), then in-place scatter to full CSR order within the
// bin's L2-resident range. No global atomics.
__global__ __launch_bounds__(512) void csort_kernel(int2* __restrict__ ep,
                                                    const int* __restrict__ cbase,
                                                    const int* __restrict__ ccnt,
                                                    int* __restrict__ node_start) {
    __shared__ int h[256];   // counts -> cursors
    __shared__ int p[256];

    const int t = threadIdx.x;
    const int bin = blockIdx.x;
    const int cb = cbase[bin];
    const int ce = cb + ccnt[bin];

    if (t < 256) h[t] = 0;
    __syncthreads();

    int2 ev[SCAP];
#pragma unroll
    for (int k = 0; k < SCAP; ++k) {
        int idx = cb + k * 512 + t;
        if (idx < ce) {
            int2 e = ep[idx];
            ev[k] = e;
            atomicAdd(&h[e.x & 255], 1);
        } else ev[k] = make_int2(-1, 0);
    }
    __syncthreads();

    int c = 0;
    if (t < 256) { c = h[t]; p[t] = c; }
    __syncthreads();
    for (int off = 1; off < 256; off <<= 1) {
        int v = 0, u = 0;
        if (t < 256) { v = p[t]; u = (t >= off) ? p[t - off] : 0; }
        __syncthreads();
        if (t < 256) p[t] = v + u;
        __syncthreads();
    }
    if (t < 256) {
        int st = cb + p[t] - c;
        node_start[bin * 256 + t] = st;
        h[t] = st;
    }
    __syncthreads();

#pragma unroll
    for (int k = 0; k < SCAP; ++k) {
        if (ev[k].x >= 0) {
            int nl = ev[k].x & 255;
            int pos = atomicAdd(&h[nl], 1);
            ep[pos] = make_int2(ev[k].x & 0xFFFFFF3F, ev[k].y);
        }
    }
}

// One block per 64-node bucket, 256 threads (4 waves) -- R3's best-measured
// configuration, unchanged. Wave w owns nodes [w*16, w*16+16): one contiguous
// CSR edge range -> wave-uniform edge batches, fp32 register accumulation,
// one bf16 flush per node.
__global__ __launch_bounds__(256, 8) void gather_fused_kernel(
        const unsigned short* __restrict__ x_bf,
        const int* __restrict__ node_start,
        const int2* __restrict__ edge_pack,
        const unsigned short* __restrict__ WT,
        const float* __restrict__ bias,
        float* __restrict__ out, int N) {
    __shared__ unsigned short accb[BN * 136];   // bf16 accum tile, 17408 B
    __shared__ int nb[BN + 1];

    const int tid = threadIdx.x;
    const int node0 = blockIdx.x * BN;
    const int w = tid >> 6, lane = tid & 63;
    unsigned int* accw = (unsigned int*)accb;   // word l of row r = feats 2l,2l+1

    for (int i = tid * 8; i < BN * 136; i += 2048)
        *(uint4*)(accb + i) = make_uint4(0u, 0u, 0u, 0u);
    if (tid <= BN) nb[tid] = node_start[node0 + tid];
    __syncthreads();

    const int js = __builtin_amdgcn_readfirstlane(nb[w * 16]);
    const int je = __builtin_amdgcn_readfirstlane(nb[w * 16 + 16]);
    const unsigned short* xl = x_bf + lane * 2;

    int cur = -1;
    float ax = 0.f, ay = 0.f;
    for (int g = js; g < je; g += 16) {
        int m = je - g; if (m > 16) m = 16;
        int2 e[16];
#pragma unroll
        for (int k = 0; k < 16; ++k) {
            int idx = g + k; if (idx >= je) idx = je - 1;
            e[k] = edge_pack[idx];
        }
        unsigned int p[16];
#pragma unroll
        for (int k = 0; k < 16; ++k)
            p[k] = *(const unsigned int*)(xl + ((e[k].x >> 8) << 7));
#pragma unroll
        for (int k = 0; k < 16; ++k) {
            if (k < m) {
                int nd = e[k].x & 63;
                if (nd != cur) {
                    if (cur >= 0)
                        accw[cur * 68 + lane] =
                            (unsigned int)f2bf(ax) | ((unsigned int)f2bf(ay) << 16);
                    cur = nd; ax = 0.f; ay = 0.f;
                }
                float v = __builtin_bit_cast(float, e[k].y);
                ax += bf2f(p[k] & 0xffffu) * v;
                ay += bf2f(p[k] >> 16) * v;
            }
        }
    }
    if (cur >= 0)
        accw[cur * 68 + lane] = (unsigned int)f2bf(ax) | ((unsigned int)f2bf(ay) << 16);
    __syncthreads();

    // ---- fused GEMM phase: out[node0..node0+64) = [x | accb] @ W + b ----
    const int quad = lane >> 4;
    const int l15  = lane & 15;
    const int colbase = w * 32;

    f32x4 acc[4][2];
#pragma unroll
    for (int rt = 0; rt < 4; ++rt) {
        acc[rt][0] = (f32x4){0.f, 0.f, 0.f, 0.f};
        acc[rt][1] = (f32x4){0.f, 0.f, 0.f, 0.f};
    }

#pragma unroll
    for (int ks = 0; ks < 8; ++ks) {
        bf16x8 wf0 = *(const bf16x8*)(WT + (size_t)(colbase + l15) * 256 + ks * 32 + quad * 8);
        bf16x8 wf1 = *(const bf16x8*)(WT + (size_t)(colbase + 16 + l15) * 256 + ks * 32 + quad * 8);
#pragma unroll
        for (int rt = 0; rt < 4; ++rt) {
            int row = rt * 16 + l15;
            bf16x8 a;
            if (ks < 4) {
                int rg = node0 + row; if (rg >= N) rg = N - 1;   // garbage rows unused
                a = *(const bf16x8*)(x_bf + (size_t)rg * D + ks * 32 + quad * 8);
            } else {
                a = *(const bf16x8*)(accb + row * 136 + (ks - 4) * 32 + quad * 8);
            }
            acc[rt][0] = __builtin_amdgcn_mfma_f32_16x16x32_bf16(a, wf0, acc[rt][0], 0, 0, 0);
            acc[rt][1] = __builtin_amdgcn_mfma_f32_16x16x32_bf16(a, wf1, acc[rt][1], 0, 0, 0);
        }
    }

#pragma unroll
    for (int ct = 0; ct < 2; ++ct) {
        int col = colbase + ct * 16 + l15;
        float bv = bias[col];
#pragma unroll
        for (int rt = 0; rt < 4; ++rt) {
#pragma unroll
            for (int rg = 0; rg < 4; ++rg) {
                int row = node0 + rt * 16 + quad * 4 + rg;
                if (row < N)
                    out[(size_t)row * D + col] = acc[rt][ct][rg] + bv;
            }
        }
    }
}

extern "C" void kernel_launch(void* const* d_in, const int* in_sizes, int n_in,
                              void* d_out, int out_size, void* d_ws, size_t ws_size,
                              hipStream_t stream) {
    const float* x    = (const float*)d_in[0];
    const int*   esrc = (const int*)d_in[1];
    const int*   edst = (const int*)d_in[2];
    const float* eval = (const float*)d_in[3];
    const float* W    = (const float*)d_in[4];
    const float* bias = (const float*)d_in[5];
    float*       out  = (float*)d_out;

    const int N  = in_sizes[0] / D;       // 100000
    const int E  = in_sizes[1];           // 1600000
    const int NG  = (N + BN - 1) / BN;    // 1563 gather blocks
    const int NCH = (E + CHUNK - 1) / CHUNK;  // 391 chunks

    // ws layout (bytes)
    char* ws = (char*)d_ws;
    unsigned short* x_bf  = (unsigned short*)ws;               // 25,600,000
    int2*           ep    = (int2*)(ws + 25600000);            // 12,800,000
    int*            hcnt  = (int*)(ws + 25600000);             // overlays ep head; dead before cfill writes ep
    unsigned short* WT    = (unsigned short*)(ws + 38400000);  // 65,536
    int*            nbg   = (int*)(ws + 38465536);             // 400,384 (NBIN*256*4)
    int*            ccnt  = (int*)(ws + 38865920);             // 2048
    int*            cbase = (int*)(ws + 38867968);             // 2048
    int*            cpos  = (int*)(ws + 38870016);             // 800,768 (512*NCH*4)

    const int n4 = N * D / 4;
    const int XB = (n4 + 255) / 256;          // 12500
    const int WB = (2 * D * D + 255) / 256;   // 128

    prep_kernel<<<XB + WB, 256, 0, stream>>>(x, x_bf, W, WT, n4, XB);
    hist_kernel<<<NCH, 512, 0, stream>>>(edst, hcnt, E);
    binscan_kernel<<<128, 256, 0, stream>>>(hcnt, cpos, ccnt, NCH);
    cscan_kernel<<<1, 256, 0, stream>>>(ccnt, cbase);
    cfill_kernel<<<NCH, 512, 0, stream>>>(esrc, edst, eval, cbase, cpos, ep, E, NCH);
    csort_kernel<<<NBIN, 512, 0, stream>>>(ep, cbase, ccnt, nbg);
    gather_fused_kernel<<<NG, 256, 0, stream>>>(x_bf, nbg, ep, WT, bias, out, N);
    (void)ws_size; (void)n_in; (void)out_size;
}